// Round 3
// baseline (14986.086 us; speedup 1.0000x reference)
//
#include <hip/hip_runtime.h>
#include <math.h>

// VQ codebook: B=32768 features x C=8192 codes, D=256.
// Pipeline: init -> cn (code norms) -> dist (fused GEMM + online argmin/min2 +
// online softmax entropy) -> refine (fp64 exact argmin for near-tie rows) ->
// gather (quantized + loss/H accumulation) -> finalize (3 scalars).
//
// dist kernel: 1 block/CU, 128 feature rows per block, full K in LDS for
// features (stride 260 floats == 4 mod 32 banks), codebook staged in 128x32
// k-tiles (stride 36). 8x8 register tile per thread (16x16 thread grid) ->
// 1 B LDS per FMA (LDS-BW bound ~1.3 ms).
//
// (Rounds 1-2: identical resubmission — container infra failure, then broker
// acquisition timeout. Kernel has not yet executed.)

#define DDIM 256
#define BM 128
#define BN 128
#define KT 32
#define PADF 260
#define PADC 36
#define MARGIN 0.02f

__global__ void init_kernel(int* flagCount, float* lossAcc, float* hAcc) {
  if (threadIdx.x == 0) { *flagCount = 0; *lossAcc = 0.f; *hAcc = 0.f; }
}

// one wave per codebook row: cn[c] = sum(cb[c,:]^2)
__global__ void cn_kernel(const float* __restrict__ cb, float* __restrict__ cn) {
  const int lane = threadIdx.x & 63;
  const int wave = threadIdx.x >> 6;
  const int c = blockIdx.x * 4 + wave;
  const float4 v = *reinterpret_cast<const float4*>(cb + (size_t)c * DDIM + lane * 4);
  float s = v.x * v.x + v.y * v.y + v.z * v.z + v.w * v.w;
  #pragma unroll
  for (int off = 1; off < 64; off <<= 1) s += __shfl_xor(s, off, 64);
  if (lane == 0) cn[c] = s;
}

__launch_bounds__(256, 1)
__global__ void dist_kernel(const float* __restrict__ feat,
                            const float* __restrict__ cb,
                            const float* __restrict__ cn,
                            float* __restrict__ Hrow,
                            int* __restrict__ aminArr,
                            int* __restrict__ flagged,
                            int* __restrict__ flagCount,
                            int C) {
  __shared__ float sF[BM * PADF];  // 133,120 B
  __shared__ float sC[BN * PADC];  //  18,432 B
  const int tid = threadIdx.x;
  const int tc = tid & 15;   // col group (16)
  const int tr = tid >> 4;   // row group (16)
  const size_t rowBase = (size_t)blockIdx.x * BM;

  // stage features: BM x 256 floats, 32 float4 per thread, coalesced
  #pragma unroll
  for (int it = 0; it < (BM * DDIM / 4) / 256; ++it) {
    int e4 = tid + it * 256;
    int r = e4 >> 6;           // 64 float4 per row
    int c = (e4 & 63) << 2;
    *reinterpret_cast<float4*>(&sF[r * PADF + c]) =
        *reinterpret_cast<const float4*>(feat + (rowBase + r) * DDIM + c);
  }

  // per-thread state for rows tr + 16*i, merged across tc at the end
  float dmin[8], dmin2[8], mm[8], ss[8], uu[8];
  int am[8];
  #pragma unroll
  for (int i = 0; i < 8; ++i) {
    dmin[i] = INFINITY; dmin2[i] = INFINITY;
    mm[i] = -1e30f; ss[i] = 0.f; uu[i] = 0.f; am[i] = 0;
  }

  const int nchunk = C / BN;
  #pragma unroll 1
  for (int ch = 0; ch < nchunk; ++ch) {
    const int cBase = ch * BN;
    float cnr[8];
    #pragma unroll
    for (int j = 0; j < 8; ++j) cnr[j] = cn[cBase + tc + 16 * j];

    float acc[8][8];
    #pragma unroll
    for (int i = 0; i < 8; ++i)
      #pragma unroll
      for (int j = 0; j < 8; ++j) acc[i][j] = 0.f;

    #pragma unroll 1
    for (int kt = 0; kt < DDIM / KT; ++kt) {
      __syncthreads();  // previous k4 consumers done with sC
      // stage sC: BN x KT = 1024 float4, 4 per thread
      #pragma unroll
      for (int it = 0; it < 4; ++it) {
        int e4 = tid + it * 256;
        int r = e4 >> 3;         // 8 float4 per row
        int c = (e4 & 7) << 2;
        *reinterpret_cast<float4*>(&sC[r * PADC + c]) =
            *reinterpret_cast<const float4*>(cb + (size_t)(cBase + r) * DDIM + kt * KT + c);
      }
      __syncthreads();
      #pragma unroll
      for (int k4 = 0; k4 < KT / 4; ++k4) {
        float4 fa[8], cv[8];
        #pragma unroll
        for (int i = 0; i < 8; ++i)
          fa[i] = *reinterpret_cast<const float4*>(&sF[(tr + 16 * i) * PADF + kt * KT + k4 * 4]);
        #pragma unroll
        for (int j = 0; j < 8; ++j)
          cv[j] = *reinterpret_cast<const float4*>(&sC[(tc + 16 * j) * PADC + k4 * 4]);
        #pragma unroll
        for (int i = 0; i < 8; ++i)
          #pragma unroll
          for (int j = 0; j < 8; ++j)
            acc[i][j] += fa[i].x * cv[j].x + fa[i].y * cv[j].y +
                         fa[i].z * cv[j].z + fa[i].w * cv[j].w;
      }
    }

    // online epilogue: dt = cn - 2*dot (fn omitted: shift-invariant)
    #pragma unroll
    for (int i = 0; i < 8; ++i) {
      #pragma unroll
      for (int j = 0; j < 8; ++j) {
        float dt = cnr[j] - 2.0f * acc[i][j];
        int cidx = cBase + tc + 16 * j;
        bool lt = dt < dmin[i];
        dmin2[i] = fminf(dmin2[i], fmaxf(dt, dmin[i]));
        am[i] = lt ? cidx : am[i];
        dmin[i] = fminf(dmin[i], dt);
        float x = -dt;
        float m2 = fmaxf(mm[i], x);
        float scl = __expf(mm[i] - m2);
        float e = __expf(x - m2);
        uu[i] = (uu[i] - (m2 - mm[i]) * ss[i]) * scl + (x - m2) * e;
        ss[i] = ss[i] * scl + e;
        mm[i] = m2;
      }
    }
  }

  // butterfly-merge across the 16 tc lanes (lane bits 0..3)
  #pragma unroll
  for (int i = 0; i < 8; ++i) {
    #pragma unroll
    for (int off = 1; off <= 8; off <<= 1) {
      float od  = __shfl_xor(dmin[i], off, 64);
      float od2 = __shfl_xor(dmin2[i], off, 64);
      int   oa  = __shfl_xor(am[i], off, 64);
      float om  = __shfl_xor(mm[i], off, 64);
      float os  = __shfl_xor(ss[i], off, 64);
      float ou  = __shfl_xor(uu[i], off, 64);
      float hi = fmaxf(dmin[i], od);
      dmin2[i] = fminf(fminf(dmin2[i], od2), hi);
      am[i] = (od < dmin[i]) ? oa : ((od == dmin[i]) ? (oa < am[i] ? oa : am[i]) : am[i]);
      dmin[i] = fminf(dmin[i], od);
      float m2 = fmaxf(mm[i], om);
      float sa = __expf(mm[i] - m2);
      float sb = __expf(om - m2);
      uu[i] = (uu[i] - (m2 - mm[i]) * ss[i]) * sa + (ou - (m2 - om) * os) * sb;
      ss[i] = ss[i] * sa + os * sb;
      mm[i] = m2;
    }
    if (tc == 0) {
      size_t row = rowBase + tr + 16 * i;
      Hrow[row] = logf(ss[i]) - uu[i] / ss[i];  // -sum p ln p
      aminArr[row] = am[i];
      if (dmin2[i] - dmin[i] < MARGIN) {
        int slot = atomicAdd(flagCount, 1);
        flagged[slot] = (int)row;
      }
    }
  }
}

// exact fp64 argmin for flagged (near-tie) rows
__global__ void refine_kernel(const float* __restrict__ feat,
                              const float* __restrict__ cb,
                              int* __restrict__ aminArr,
                              const int* __restrict__ flagged,
                              const int* __restrict__ flagCount,
                              int C) {
  const int lane = threadIdx.x & 63;
  const int wave = threadIdx.x >> 6;
  __shared__ double bmin[4];
  __shared__ int bidx[4];
  const int nf = *flagCount;
  for (int f = blockIdx.x; f < nf; f += gridDim.x) {
    const int row = flagged[f];
    const float4 fv = *reinterpret_cast<const float4*>(feat + (size_t)row * DDIM + lane * 4);
    double lmin = 1e300;
    int lidx = 0;
    for (int c = wave; c < C; c += 4) {
      const float4 cv = *reinterpret_cast<const float4*>(cb + (size_t)c * DDIM + lane * 4);
      double d0 = (double)fv.x - (double)cv.x;
      double d1 = (double)fv.y - (double)cv.y;
      double d2 = (double)fv.z - (double)cv.z;
      double d3 = (double)fv.w - (double)cv.w;
      double sum = d0 * d0 + d1 * d1 + d2 * d2 + d3 * d3;
      #pragma unroll
      for (int off = 1; off < 64; off <<= 1) sum += __shfl_xor(sum, off, 64);
      if (sum < lmin) { lmin = sum; lidx = c; }  // ascending c: keeps first
    }
    if (lane == 0) { bmin[wave] = lmin; bidx[wave] = lidx; }
    __syncthreads();
    if (threadIdx.x == 0) {
      double m = bmin[0]; int ix = bidx[0];
      for (int w = 1; w < 4; ++w)
        if (bmin[w] < m) { m = bmin[w]; ix = bidx[w]; }
      aminArr[row] = ix;
    }
    __syncthreads();
  }
}

__launch_bounds__(256)
__global__ void gather_kernel(const float* __restrict__ feat,
                              const float* __restrict__ cb,
                              const int* __restrict__ aminArr,
                              const float* __restrict__ Hrow,
                              float* __restrict__ out,
                              float* lossAcc, float* hAcc) {
  const int tid = threadIdx.x;
  const int lane = tid & 63;
  const int wave = tid >> 6;
  const size_t base = (size_t)blockIdx.x * 64;
  float lsum = 0.f;
  #pragma unroll 1
  for (int r = wave; r < 64; r += 4) {
    const size_t row = base + r;
    const int q = aminArr[row];
    const float4 cv = *reinterpret_cast<const float4*>(cb + (size_t)q * DDIM + lane * 4);
    const float4 fv = *reinterpret_cast<const float4*>(feat + row * DDIM + lane * 4);
    *reinterpret_cast<float4*>(out + row * DDIM + lane * 4) = cv;  // STE fwd == quantized
    const float dx = cv.x - fv.x, dy = cv.y - fv.y, dz = cv.z - fv.z, dw = cv.w - fv.w;
    lsum += dx * dx + dy * dy + dz * dz + dw * dw;
  }
  #pragma unroll
  for (int off = 1; off < 64; off <<= 1) lsum += __shfl_xor(lsum, off, 64);
  __shared__ float wsum[4];
  if (lane == 0) wsum[wave] = lsum;
  __syncthreads();
  if (tid == 0) atomicAdd(lossAcc, wsum[0] + wsum[1] + wsum[2] + wsum[3]);
  if (wave == 0) {
    float h = Hrow[base + lane];
    #pragma unroll
    for (int off = 1; off < 64; off <<= 1) h += __shfl_xor(h, off, 64);
    if (lane == 0) atomicAdd(hAcc, h);
  }
}

__global__ void finalize_kernel(const float* lossAcc, const float* hAcc,
                                float* out, size_t M, float invBD, float invB) {
  if (threadIdx.x == 0) {
    float L = *lossAcc * invBD;
    out[M] = L;       // codebook_loss
    out[M + 1] = L;   // commitment_loss (same forward value)
    out[M + 2] = *hAcc * invB;  // code_entropy
  }
}

extern "C" void kernel_launch(void* const* d_in, const int* in_sizes, int n_in,
                              void* d_out, int out_size, void* d_ws, size_t ws_size,
                              hipStream_t stream) {
  (void)n_in; (void)out_size; (void)ws_size;
  const float* feat = (const float*)d_in[0];
  const float* cb   = (const float*)d_in[1];
  const int B = in_sizes[0] / DDIM;  // 32768
  const int C = in_sizes[1] / DDIM;  // 8192
  float* out = (float*)d_out;

  float* cn      = (float*)d_ws;            // C
  float* Hrow    = cn + C;                  // B
  int*   amin    = (int*)(Hrow + B);        // B
  int*   flagged = amin + B;                // B
  int*   flagCount = flagged + B;           // 1
  float* lossAcc = (float*)(flagCount + 1); // 1
  float* hAcc    = lossAcc + 1;             // 1

  init_kernel<<<1, 64, 0, stream>>>(flagCount, lossAcc, hAcc);
  cn_kernel<<<C / 4, 256, 0, stream>>>(cb, cn);
  dist_kernel<<<B / BM, 256, 0, stream>>>(feat, cb, cn, Hrow, amin, flagged, flagCount, C);
  refine_kernel<<<128, 256, 0, stream>>>(feat, cb, amin, flagged, flagCount, C);
  gather_kernel<<<B / 64, 256, 0, stream>>>(feat, cb, amin, Hrow, out, lossAcc, hAcc);
  finalize_kernel<<<1, 64, 0, stream>>>(lossAcc, hAcc, out,
                                        (size_t)B * DDIM,
                                        1.0f / ((float)B * (float)DDIM),
                                        1.0f / (float)B);
}

// Round 4
// 3626.117 us; speedup vs baseline: 4.1328x; 4.1328x over previous
//
#include <hip/hip_runtime.h>
#include <math.h>

// VQ codebook: B=32768 features x C=8192 codes, D=256.
// Pipeline: init -> cn (code norms) -> dist (fused GEMM + online argmin/min2 +
// online softmax entropy) -> refine (fp64 exact argmin for near-tie rows) ->
// gather (quantized + loss/H accumulation) -> finalize (3 scalars).
//
// Round 3 -> 4 change: kill the scratch spill (34.9 GB/dispatch of HBM writes,
// VGPR_Count=256 cap). k4 loop was fully unrolled with fa[8]+cv[8] float4
// arrays -> register demand >> 256. Now: cv loaded per-j (4 VGPRs), k4 loop
// unroll-capped at 2, cn prefetch moved to epilogue. Target ~170 live VGPRs.

#define DDIM 256
#define BM 128
#define BN 128
#define KT 32
#define PADF 260
#define PADC 36
#define MARGIN 0.02f

__global__ void init_kernel(int* flagCount, float* lossAcc, float* hAcc) {
  if (threadIdx.x == 0) { *flagCount = 0; *lossAcc = 0.f; *hAcc = 0.f; }
}

// one wave per codebook row: cn[c] = sum(cb[c,:]^2)
__global__ void cn_kernel(const float* __restrict__ cb, float* __restrict__ cn) {
  const int lane = threadIdx.x & 63;
  const int wave = threadIdx.x >> 6;
  const int c = blockIdx.x * 4 + wave;
  const float4 v = *reinterpret_cast<const float4*>(cb + (size_t)c * DDIM + lane * 4);
  float s = v.x * v.x + v.y * v.y + v.z * v.z + v.w * v.w;
  #pragma unroll
  for (int off = 1; off < 64; off <<= 1) s += __shfl_xor(s, off, 64);
  if (lane == 0) cn[c] = s;
}

__launch_bounds__(256, 1)
__global__ void dist_kernel(const float* __restrict__ feat,
                            const float* __restrict__ cb,
                            const float* __restrict__ cn,
                            float* __restrict__ Hrow,
                            int* __restrict__ aminArr,
                            int* __restrict__ flagged,
                            int* __restrict__ flagCount,
                            int C) {
  __shared__ float sF[BM * PADF];  // 133,120 B
  __shared__ float sC[BN * PADC];  //  18,432 B
  const int tid = threadIdx.x;
  const int tc = tid & 15;   // col group (16)
  const int tr = tid >> 4;   // row group (16)
  const size_t rowBase = (size_t)blockIdx.x * BM;

  // stage features: BM x 256 floats, 32 float4 per thread, coalesced
  #pragma unroll
  for (int it = 0; it < (BM * DDIM / 4) / 256; ++it) {
    int e4 = tid + it * 256;
    int r = e4 >> 6;           // 64 float4 per row
    int c = (e4 & 63) << 2;
    *reinterpret_cast<float4*>(&sF[r * PADF + c]) =
        *reinterpret_cast<const float4*>(feat + (rowBase + r) * DDIM + c);
  }

  // per-thread state for rows tr + 16*i, merged across tc at the end
  float dmin[8], dmin2[8], mm[8], ss[8], uu[8];
  int am[8];
  #pragma unroll
  for (int i = 0; i < 8; ++i) {
    dmin[i] = INFINITY; dmin2[i] = INFINITY;
    mm[i] = -1e30f; ss[i] = 0.f; uu[i] = 0.f; am[i] = 0;
  }

  const int nchunk = C / BN;
  #pragma unroll 1
  for (int ch = 0; ch < nchunk; ++ch) {
    const int cBase = ch * BN;

    float acc[8][8];
    #pragma unroll
    for (int i = 0; i < 8; ++i)
      #pragma unroll
      for (int j = 0; j < 8; ++j) acc[i][j] = 0.f;

    #pragma unroll 1
    for (int kt = 0; kt < DDIM / KT; ++kt) {
      __syncthreads();  // previous consumers done with sC (covers sF stage on first iter)
      // stage sC: BN x KT = 1024 float4, 4 per thread
      #pragma unroll
      for (int it = 0; it < 4; ++it) {
        int e4 = tid + it * 256;
        int r = e4 >> 3;         // 8 float4 per row
        int c = (e4 & 7) << 2;
        *reinterpret_cast<float4*>(&sC[r * PADC + c]) =
            *reinterpret_cast<const float4*>(cb + (size_t)(cBase + r) * DDIM + kt * KT + c);
      }
      __syncthreads();
      const float* fbase = &sF[tr * PADF + kt * KT];
      const float* cbase = &sC[tc * PADC];
      #pragma unroll 2
      for (int k4 = 0; k4 < KT / 4; ++k4) {
        float4 fa[8];
        #pragma unroll
        for (int i = 0; i < 8; ++i)
          fa[i] = *reinterpret_cast<const float4*>(fbase + i * (16 * PADF) + k4 * 4);
        #pragma unroll
        for (int j = 0; j < 8; ++j) {
          const float4 cv = *reinterpret_cast<const float4*>(cbase + j * (16 * PADC) + k4 * 4);
          #pragma unroll
          for (int i = 0; i < 8; ++i)
            acc[i][j] += fa[i].x * cv.x + fa[i].y * cv.y +
                         fa[i].z * cv.z + fa[i].w * cv.w;
        }
      }
    }

    // online epilogue: dt = cn - 2*dot (fn omitted: shift-invariant)
    #pragma unroll
    for (int j = 0; j < 8; ++j) {
      const int cidx = cBase + tc + 16 * j;
      const float cnj = cn[cidx];
      #pragma unroll
      for (int i = 0; i < 8; ++i) {
        float dt = cnj - 2.0f * acc[i][j];
        bool lt = dt < dmin[i];
        dmin2[i] = fminf(dmin2[i], fmaxf(dt, dmin[i]));
        am[i] = lt ? cidx : am[i];
        dmin[i] = fminf(dmin[i], dt);
        float x = -dt;
        float m2 = fmaxf(mm[i], x);
        float scl = __expf(mm[i] - m2);
        float e = __expf(x - m2);
        uu[i] = (uu[i] - (m2 - mm[i]) * ss[i]) * scl + (x - m2) * e;
        ss[i] = ss[i] * scl + e;
        mm[i] = m2;
      }
    }
  }

  // butterfly-merge across the 16 tc lanes (lane bits 0..3)
  #pragma unroll
  for (int i = 0; i < 8; ++i) {
    #pragma unroll
    for (int off = 1; off <= 8; off <<= 1) {
      float od  = __shfl_xor(dmin[i], off, 64);
      float od2 = __shfl_xor(dmin2[i], off, 64);
      int   oa  = __shfl_xor(am[i], off, 64);
      float om  = __shfl_xor(mm[i], off, 64);
      float os  = __shfl_xor(ss[i], off, 64);
      float ou  = __shfl_xor(uu[i], off, 64);
      float hi = fmaxf(dmin[i], od);
      dmin2[i] = fminf(fminf(dmin2[i], od2), hi);
      am[i] = (od < dmin[i]) ? oa : ((od == dmin[i]) ? (oa < am[i] ? oa : am[i]) : am[i]);
      dmin[i] = fminf(dmin[i], od);
      float m2 = fmaxf(mm[i], om);
      float sa = __expf(mm[i] - m2);
      float sb = __expf(om - m2);
      uu[i] = (uu[i] - (m2 - mm[i]) * ss[i]) * sa + (ou - (m2 - om) * os) * sb;
      ss[i] = ss[i] * sa + os * sb;
      mm[i] = m2;
    }
    if (tc == 0) {
      size_t row = rowBase + tr + 16 * i;
      Hrow[row] = logf(ss[i]) - uu[i] / ss[i];  // -sum p ln p
      aminArr[row] = am[i];
      if (dmin2[i] - dmin[i] < MARGIN) {
        int slot = atomicAdd(flagCount, 1);
        flagged[slot] = (int)row;
      }
    }
  }
}

// exact fp64 argmin for flagged (near-tie) rows
__global__ void refine_kernel(const float* __restrict__ feat,
                              const float* __restrict__ cb,
                              int* __restrict__ aminArr,
                              const int* __restrict__ flagged,
                              const int* __restrict__ flagCount,
                              int C) {
  const int lane = threadIdx.x & 63;
  const int wave = threadIdx.x >> 6;
  __shared__ double bmin[4];
  __shared__ int bidx[4];
  const int nf = *flagCount;
  for (int f = blockIdx.x; f < nf; f += gridDim.x) {
    const int row = flagged[f];
    const float4 fv = *reinterpret_cast<const float4*>(feat + (size_t)row * DDIM + lane * 4);
    double lmin = 1e300;
    int lidx = 0;
    for (int c = wave; c < C; c += 4) {
      const float4 cv = *reinterpret_cast<const float4*>(cb + (size_t)c * DDIM + lane * 4);
      double d0 = (double)fv.x - (double)cv.x;
      double d1 = (double)fv.y - (double)cv.y;
      double d2 = (double)fv.z - (double)cv.z;
      double d3 = (double)fv.w - (double)cv.w;
      double sum = d0 * d0 + d1 * d1 + d2 * d2 + d3 * d3;
      #pragma unroll
      for (int off = 1; off < 64; off <<= 1) sum += __shfl_xor(sum, off, 64);
      if (sum < lmin) { lmin = sum; lidx = c; }  // ascending c: keeps first
    }
    if (lane == 0) { bmin[wave] = lmin; bidx[wave] = lidx; }
    __syncthreads();
    if (threadIdx.x == 0) {
      double m = bmin[0]; int ix = bidx[0];
      for (int w = 1; w < 4; ++w)
        if (bmin[w] < m) { m = bmin[w]; ix = bidx[w]; }
      aminArr[row] = ix;
    }
    __syncthreads();
  }
}

__launch_bounds__(256)
__global__ void gather_kernel(const float* __restrict__ feat,
                              const float* __restrict__ cb,
                              const int* __restrict__ aminArr,
                              const float* __restrict__ Hrow,
                              float* __restrict__ out,
                              float* lossAcc, float* hAcc) {
  const int tid = threadIdx.x;
  const int lane = tid & 63;
  const int wave = tid >> 6;
  const size_t base = (size_t)blockIdx.x * 64;
  float lsum = 0.f;
  #pragma unroll 1
  for (int r = wave; r < 64; r += 4) {
    const size_t row = base + r;
    const int q = aminArr[row];
    const float4 cv = *reinterpret_cast<const float4*>(cb + (size_t)q * DDIM + lane * 4);
    const float4 fv = *reinterpret_cast<const float4*>(feat + row * DDIM + lane * 4);
    *reinterpret_cast<float4*>(out + row * DDIM + lane * 4) = cv;  // STE fwd == quantized
    const float dx = cv.x - fv.x, dy = cv.y - fv.y, dz = cv.z - fv.z, dw = cv.w - fv.w;
    lsum += dx * dx + dy * dy + dz * dz + dw * dw;
  }
  #pragma unroll
  for (int off = 1; off < 64; off <<= 1) lsum += __shfl_xor(lsum, off, 64);
  __shared__ float wsum[4];
  if (lane == 0) wsum[wave] = lsum;
  __syncthreads();
  if (tid == 0) atomicAdd(lossAcc, wsum[0] + wsum[1] + wsum[2] + wsum[3]);
  if (wave == 0) {
    float h = Hrow[base + lane];
    #pragma unroll
    for (int off = 1; off < 64; off <<= 1) h += __shfl_xor(h, off, 64);
    if (lane == 0) atomicAdd(hAcc, h);
  }
}

__global__ void finalize_kernel(const float* lossAcc, const float* hAcc,
                                float* out, size_t M, float invBD, float invB) {
  if (threadIdx.x == 0) {
    float L = *lossAcc * invBD;
    out[M] = L;       // codebook_loss
    out[M + 1] = L;   // commitment_loss (same forward value)
    out[M + 2] = *hAcc * invB;  // code_entropy
  }
}

extern "C" void kernel_launch(void* const* d_in, const int* in_sizes, int n_in,
                              void* d_out, int out_size, void* d_ws, size_t ws_size,
                              hipStream_t stream) {
  (void)n_in; (void)out_size; (void)ws_size;
  const float* feat = (const float*)d_in[0];
  const float* cb   = (const float*)d_in[1];
  const int B = in_sizes[0] / DDIM;  // 32768
  const int C = in_sizes[1] / DDIM;  // 8192
  float* out = (float*)d_out;

  float* cn      = (float*)d_ws;            // C
  float* Hrow    = cn + C;                  // B
  int*   amin    = (int*)(Hrow + B);        // B
  int*   flagged = amin + B;                // B
  int*   flagCount = flagged + B;           // 1
  float* lossAcc = (float*)(flagCount + 1); // 1
  float* hAcc    = lossAcc + 1;             // 1

  init_kernel<<<1, 64, 0, stream>>>(flagCount, lossAcc, hAcc);
  cn_kernel<<<C / 4, 256, 0, stream>>>(cb, cn);
  dist_kernel<<<B / BM, 256, 0, stream>>>(feat, cb, cn, Hrow, amin, flagged, flagCount, C);
  refine_kernel<<<128, 256, 0, stream>>>(feat, cb, amin, flagged, flagCount, C);
  gather_kernel<<<B / 64, 256, 0, stream>>>(feat, cb, amin, Hrow, out, lossAcc, hAcc);
  finalize_kernel<<<1, 64, 0, stream>>>(lossAcc, hAcc, out,
                                        (size_t)B * DDIM,
                                        1.0f / ((float)B * (float)DDIM),
                                        1.0f / (float)B);
}

// Round 5
// 1569.302 us; speedup vs baseline: 9.5495x; 2.3107x over previous
//
#include <hip/hip_runtime.h>
#include <math.h>

// VQ codebook: B=32768 x C=8192, D=256.
// Round 5: dist GEMM moved to bf16 hi/lo-split MFMA (3-term, fl*cl dropped).
// init -> cvt_cb (fp32 codebook -> bf16 hi/lo) -> cn -> dist (MFMA GEMM +
// online argmin/min2 + online softmax entropy in log2 units) -> refine (fp64
// exact argmin for near-tie rows) -> gather -> finalize.
//
// dist: 256 blocks (1/CU), 4 waves, chunk = 128 rows x 128 codes, KT=64.
// Wave strip 32 rows x 128 cols, MFMA 16x16x32 bf16, acc[2][8] f32x4.
// LDS: sFhi/sFlo 128x256 bf16 (64KB each) + sChi/sClo 128x64 bf16 (16KB each)
// = 163840 B exactly. XOR swizzle byte^=((row&7)<<4) on rows (2-way, free).
// sC staged via global_load_lds(16B) with pre-swizzled global source.

#define DDIM 256
#define BM 128
#define BN 128
#define LOG2E 1.44269504f
#define NEG2L (-2.88539008f)
#define LN2 0.69314718f
#define MARGIN_Y 0.0288539f   // 0.02 * log2e

typedef short bf16x8 __attribute__((ext_vector_type(8)));
typedef unsigned short ushort8 __attribute__((ext_vector_type(8)));
typedef float f32x4 __attribute__((ext_vector_type(4)));

__device__ __forceinline__ unsigned short f2bf(float f) {
  unsigned u = __float_as_uint(f);
  return (unsigned short)((u + 0x7FFF + ((u >> 16) & 1)) >> 16);
}
__device__ __forceinline__ float bf2f(unsigned short h) {
  return __uint_as_float(((unsigned)h) << 16);
}
__device__ __forceinline__ void gload_lds16(const void* g, void* l) {
  __builtin_amdgcn_global_load_lds(
      (const __attribute__((address_space(1))) void*)g,
      (__attribute__((address_space(3))) void*)l, 16, 0, 0);
}

__global__ void init_kernel(int* flagCount, float* lossAcc, float* hAcc) {
  if (threadIdx.x == 0) { *flagCount = 0; *lossAcc = 0.f; *hAcc = 0.f; }
}

// elementwise fp32 -> bf16 hi + bf16 lo residual (8 elems/thread)
__global__ void cvt_cb_kernel(const float* __restrict__ cb,
                              unsigned short* __restrict__ hi,
                              unsigned short* __restrict__ lo) {
  const size_t base = ((size_t)blockIdx.x * 256 + threadIdx.x) * 8;
  const float4 f0 = *reinterpret_cast<const float4*>(cb + base);
  const float4 f1 = *reinterpret_cast<const float4*>(cb + base + 4);
  float fv[8] = {f0.x, f0.y, f0.z, f0.w, f1.x, f1.y, f1.z, f1.w};
  ushort8 h, l;
  #pragma unroll
  for (int e = 0; e < 8; ++e) {
    unsigned short hh = f2bf(fv[e]);
    h[e] = hh;
    l[e] = f2bf(fv[e] - bf2f(hh));
  }
  *reinterpret_cast<ushort8*>(hi + base) = h;
  *reinterpret_cast<ushort8*>(lo + base) = l;
}

// one wave per codebook row: cn[c] = sum(cb[c,:]^2)  (exact fp32 source)
__global__ void cn_kernel(const float* __restrict__ cb, float* __restrict__ cn) {
  const int lane = threadIdx.x & 63;
  const int wave = threadIdx.x >> 6;
  const int c = blockIdx.x * 4 + wave;
  const float4 v = *reinterpret_cast<const float4*>(cb + (size_t)c * DDIM + lane * 4);
  float s = v.x * v.x + v.y * v.y + v.z * v.z + v.w * v.w;
  #pragma unroll
  for (int off = 1; off < 64; off <<= 1) s += __shfl_xor(s, off, 64);
  if (lane == 0) cn[c] = s;
}

__launch_bounds__(256, 1)
__global__ void dist_kernel(const float* __restrict__ feat,
                            const unsigned short* __restrict__ cbhi,
                            const unsigned short* __restrict__ cblo,
                            const float* __restrict__ cn,
                            float* __restrict__ Hrow,
                            int* __restrict__ aminArr,
                            int* __restrict__ flagged,
                            int* __restrict__ flagCount,
                            int C) {
  __shared__ unsigned short sFhi[BM * DDIM];  // 65536 B, rows of 512 B, swizzled
  __shared__ unsigned short sFlo[BM * DDIM];  // 65536 B
  __shared__ unsigned short sChi[BN * 64];    // 16384 B, rows of 128 B, swizzled
  __shared__ unsigned short sClo[BN * 64];    // 16384 B   (total 163840 B)
  const int tid = threadIdx.x;
  const int lane = tid & 63;
  const int w = tid >> 6;        // wave 0..3 -> rows w*32..w*32+31
  const int lr = lane & 15;      // row-in-tile (A) / col-in-tile (B)
  const int g = lane >> 4;       // k-group (4 x 8 elems = K32 frag)
  const size_t rowBase = (size_t)blockIdx.x * BM;

  char* sFhiB = (char*)sFhi; char* sFloB = (char*)sFlo;
  char* sChiB = (char*)sChi; char* sCloB = (char*)sClo;

  // ---- stage features: fp32 -> bf16 hi/lo, swizzled rows of 512 B ----
  #pragma unroll 1
  for (int it = 0; it < 16; ++it) {
    int idx8 = tid + it * 256;        // float8 granule, 4096 total
    int row = idx8 >> 5;              // 32 granules per 256-f row
    int k8 = idx8 & 31;
    const float* fp = feat + (rowBase + row) * DDIM + k8 * 8;
    const float4 f0 = *reinterpret_cast<const float4*>(fp);
    const float4 f1 = *reinterpret_cast<const float4*>(fp + 4);
    float fv[8] = {f0.x, f0.y, f0.z, f0.w, f1.x, f1.y, f1.z, f1.w};
    ushort8 h, l;
    #pragma unroll
    for (int e = 0; e < 8; ++e) {
      unsigned short hh = f2bf(fv[e]);
      h[e] = hh;
      l[e] = f2bf(fv[e] - bf2f(hh));
    }
    int off = (k8 * 16) ^ ((row & 7) << 4);
    *reinterpret_cast<ushort8*>(sFhiB + row * 512 + off) = h;
    *reinterpret_cast<ushort8*>(sFloB + row * 512 + off) = l;
  }

  // per-lane state: 8 rows (mt 0..1 x r 0..3), 8 cols (nt 0..7, col=nt*16+lr)
  float dminY[8], dmin2Y[8], mmY[8], ss[8], vv[8];
  int am[8];
  #pragma unroll
  for (int i = 0; i < 8; ++i) {
    dminY[i] = INFINITY; dmin2Y[i] = INFINITY;
    mmY[i] = 1e9f; ss[i] = 0.f; vv[i] = 0.f; am[i] = 0;
  }

  const int nchunk = C / BN;
  #pragma unroll 1
  for (int ch = 0; ch < nchunk; ++ch) {
    const int cBase = ch * BN;
    float cnL[8];
    #pragma unroll
    for (int nt = 0; nt < 8; ++nt)
      cnL[nt] = cn[cBase + nt * 16 + lr] * LOG2E;

    f32x4 acc[2][8];
    #pragma unroll
    for (int mt = 0; mt < 2; ++mt)
      #pragma unroll
      for (int nt = 0; nt < 8; ++nt)
        acc[mt][nt] = (f32x4){0.f, 0.f, 0.f, 0.f};

    #pragma unroll 1
    for (int kt = 0; kt < 4; ++kt) {   // K-tiles of 64
      __syncthreads();   // previous sC consumers done (covers sF stage @first)
      // stage sC[kt]: wave w fills bytes [w*4096, w*4096+4096) of hi and lo.
      // Linear LDS dest (base + lane*16), pre-swizzled global source.
      #pragma unroll
      for (int it = 0; it < 4; ++it) {
        int L = w * 4096 + it * 1024 + lane * 16;
        int code = L >> 7;            // 128 B per code row
        int kb = L & 127;
        size_t srcOff = (((size_t)(cBase + code)) << 9) + (size_t)kt * 128 +
                        (kb ^ ((code & 7) << 4));
        gload_lds16((const char*)cbhi + srcOff, sChiB + w * 4096 + it * 1024);
        gload_lds16((const char*)cblo + srcOff, sCloB + w * 4096 + it * 1024);
      }
      __syncthreads();   // staged data visible (barrier drains vmcnt)

      #pragma unroll
      for (int ks = 0; ks < 2; ++ks) {  // two K=32 MFMA steps
        bf16x8 ahi[2], alo[2];
        #pragma unroll
        for (int mt = 0; mt < 2; ++mt) {
          int row = w * 32 + mt * 16 + lr;
          int off = (kt * 128 + ks * 64 + g * 16) ^ ((row & 7) << 4);
          ahi[mt] = *reinterpret_cast<const bf16x8*>(sFhiB + row * 512 + off);
          alo[mt] = *reinterpret_cast<const bf16x8*>(sFloB + row * 512 + off);
        }
        #pragma unroll
        for (int nt = 0; nt < 8; ++nt) {
          int code = nt * 16 + lr;
          int boff = (ks * 64 + g * 16) ^ ((code & 7) << 4);
          bf16x8 bhi = *reinterpret_cast<const bf16x8*>(sChiB + code * 128 + boff);
          bf16x8 blo = *reinterpret_cast<const bf16x8*>(sCloB + code * 128 + boff);
          #pragma unroll
          for (int mt = 0; mt < 2; ++mt) {
            acc[mt][nt] = __builtin_amdgcn_mfma_f32_16x16x32_bf16(ahi[mt], bhi, acc[mt][nt], 0, 0, 0);
            acc[mt][nt] = __builtin_amdgcn_mfma_f32_16x16x32_bf16(alo[mt], bhi, acc[mt][nt], 0, 0, 0);
            acc[mt][nt] = __builtin_amdgcn_mfma_f32_16x16x32_bf16(ahi[mt], blo, acc[mt][nt], 0, 0, 0);
          }
        }
      }
    }

    // ---- online epilogue in log2 units: y = dt*log2e = fma(dot, -2L, cnL) ----
    #pragma unroll
    for (int mt = 0; mt < 2; ++mt) {
      #pragma unroll
      for (int r = 0; r < 4; ++r) {
        const int s = mt * 4 + r;
        float y[8];
        #pragma unroll
        for (int nt = 0; nt < 8; ++nt)
          y[nt] = fmaf(acc[mt][nt][r], NEG2L, cnL[nt]);
        float m8 = fminf(fminf(fminf(y[0], y[1]), fminf(y[2], y[3])),
                         fminf(fminf(y[4], y[5]), fminf(y[6], y[7])));
        float nm = fminf(mmY[s], m8);
        float scl = __builtin_amdgcn_exp2f(nm - mmY[s]);  // ==1 when no update
        ss[s] *= scl; vv[s] *= scl; mmY[s] = nm;
        #pragma unroll
        for (int nt = 0; nt < 8; ++nt) {
          float e = __builtin_amdgcn_exp2f(nm - y[nt]);
          ss[s] += e;
          vv[s] = fmaf(y[nt], e, vv[s]);
          int cidx = cBase + nt * 16 + lr;
          bool lt = y[nt] < dminY[s];
          dmin2Y[s] = fminf(dmin2Y[s], fmaxf(y[nt], dminY[s]));
          am[s] = lt ? cidx : am[s];
          dminY[s] = fminf(dminY[s], y[nt]);
        }
      }
    }
  }

  // ---- butterfly-merge across the 16 lanes of each k-group (bits 0..3) ----
  #pragma unroll
  for (int i = 0; i < 8; ++i) {
    #pragma unroll
    for (int off = 1; off <= 8; off <<= 1) {
      float od = __shfl_xor(dminY[i], off, 64);
      float od2 = __shfl_xor(dmin2Y[i], off, 64);
      int oa = __shfl_xor(am[i], off, 64);
      float om = __shfl_xor(mmY[i], off, 64);
      float os = __shfl_xor(ss[i], off, 64);
      float ov = __shfl_xor(vv[i], off, 64);
      float hi = fmaxf(dminY[i], od);
      dmin2Y[i] = fminf(fminf(dmin2Y[i], od2), hi);
      am[i] = (od < dminY[i]) ? oa : ((od == dminY[i]) ? (oa < am[i] ? oa : am[i]) : am[i]);
      dminY[i] = fminf(dminY[i], od);
      float nm = fminf(mmY[i], om);
      float sa = __builtin_amdgcn_exp2f(nm - mmY[i]);
      float sb = __builtin_amdgcn_exp2f(nm - om);
      ss[i] = ss[i] * sa + os * sb;
      vv[i] = vv[i] * sa + ov * sb;
      mmY[i] = nm;
    }
    if (lr == 0) {
      size_t row = rowBase + w * 32 + (i >> 2) * 16 + 4 * g + (i & 3);
      Hrow[row] = logf(ss[i]) + LN2 * (vv[i] / ss[i] - mmY[i]);
      aminArr[row] = am[i];
      if (dmin2Y[i] - dminY[i] < MARGIN_Y) {
        int slot = atomicAdd(flagCount, 1);
        flagged[slot] = (int)row;
      }
    }
  }
}

// exact fp64 argmin for flagged (near-tie) rows, from original fp32 data
__global__ void refine_kernel(const float* __restrict__ feat,
                              const float* __restrict__ cb,
                              int* __restrict__ aminArr,
                              const int* __restrict__ flagged,
                              const int* __restrict__ flagCount,
                              int C) {
  const int lane = threadIdx.x & 63;
  const int wave = threadIdx.x >> 6;
  __shared__ double bmin[4];
  __shared__ int bidx[4];
  const int nf = *flagCount;
  for (int f = blockIdx.x; f < nf; f += gridDim.x) {
    const int row = flagged[f];
    const float4 fv = *reinterpret_cast<const float4*>(feat + (size_t)row * DDIM + lane * 4);
    double lmin = 1e300;
    int lidx = 0;
    for (int c = wave; c < C; c += 4) {
      const float4 cv = *reinterpret_cast<const float4*>(cb + (size_t)c * DDIM + lane * 4);
      double d0 = (double)fv.x - (double)cv.x;
      double d1 = (double)fv.y - (double)cv.y;
      double d2 = (double)fv.z - (double)cv.z;
      double d3 = (double)fv.w - (double)cv.w;
      double sum = d0 * d0 + d1 * d1 + d2 * d2 + d3 * d3;
      #pragma unroll
      for (int off = 1; off < 64; off <<= 1) sum += __shfl_xor(sum, off, 64);
      if (sum < lmin) { lmin = sum; lidx = c; }
    }
    if (lane == 0) { bmin[wave] = lmin; bidx[wave] = lidx; }
    __syncthreads();
    if (threadIdx.x == 0) {
      double m = bmin[0]; int ix = bidx[0];
      for (int wv = 1; wv < 4; ++wv)
        if (bmin[wv] < m) { m = bmin[wv]; ix = bidx[wv]; }
      aminArr[row] = ix;
    }
    __syncthreads();
  }
}

__launch_bounds__(256)
__global__ void gather_kernel(const float* __restrict__ feat,
                              const float* __restrict__ cb,
                              const int* __restrict__ aminArr,
                              const float* __restrict__ Hrow,
                              float* __restrict__ out,
                              float* lossAcc, float* hAcc) {
  const int tid = threadIdx.x;
  const int lane = tid & 63;
  const int wave = tid >> 6;
  const size_t base = (size_t)blockIdx.x * 64;
  float lsum = 0.f;
  #pragma unroll 1
  for (int r = wave; r < 64; r += 4) {
    const size_t row = base + r;
    const int q = aminArr[row];
    const float4 cv = *reinterpret_cast<const float4*>(cb + (size_t)q * DDIM + lane * 4);
    const float4 fv = *reinterpret_cast<const float4*>(feat + row * DDIM + lane * 4);
    *reinterpret_cast<float4*>(out + row * DDIM + lane * 4) = cv;
    const float dx = cv.x - fv.x, dy = cv.y - fv.y, dz = cv.z - fv.z, dw = cv.w - fv.w;
    lsum += dx * dx + dy * dy + dz * dz + dw * dw;
  }
  #pragma unroll
  for (int off = 1; off < 64; off <<= 1) lsum += __shfl_xor(lsum, off, 64);
  __shared__ float wsum[4];
  if (lane == 0) wsum[wave] = lsum;
  __syncthreads();
  if (tid == 0) atomicAdd(lossAcc, wsum[0] + wsum[1] + wsum[2] + wsum[3]);
  if (wave == 0) {
    float h = Hrow[base + lane];
    #pragma unroll
    for (int off = 1; off < 64; off <<= 1) h += __shfl_xor(h, off, 64);
    if (lane == 0) atomicAdd(hAcc, h);
  }
}

__global__ void finalize_kernel(const float* lossAcc, const float* hAcc,
                                float* out, size_t M, float invBD, float invB) {
  if (threadIdx.x == 0) {
    float L = *lossAcc * invBD;
    out[M] = L;
    out[M + 1] = L;
    out[M + 2] = *hAcc * invB;
  }
}

extern "C" void kernel_launch(void* const* d_in, const int* in_sizes, int n_in,
                              void* d_out, int out_size, void* d_ws, size_t ws_size,
                              hipStream_t stream) {
  (void)n_in; (void)out_size; (void)ws_size;
  const float* feat = (const float*)d_in[0];
  const float* cb   = (const float*)d_in[1];
  const int B = in_sizes[0] / DDIM;  // 32768
  const int C = in_sizes[1] / DDIM;  // 8192
  float* out = (float*)d_out;

  unsigned short* cbhi = (unsigned short*)d_ws;          // C*DDIM bf16
  unsigned short* cblo = cbhi + (size_t)C * DDIM;        // C*DDIM bf16
  float* cn      = (float*)(cblo + (size_t)C * DDIM);    // C
  float* Hrow    = cn + C;                               // B
  int*   amin    = (int*)(Hrow + B);                     // B
  int*   flagged = amin + B;                             // B
  int*   flagCount = flagged + B;                        // 1
  float* lossAcc = (float*)(flagCount + 1);              // 1
  float* hAcc    = lossAcc + 1;                          // 1

  init_kernel<<<1, 64, 0, stream>>>(flagCount, lossAcc, hAcc);
  cvt_cb_kernel<<<(C * DDIM) / (256 * 8), 256, 0, stream>>>(cb, cbhi, cblo);
  cn_kernel<<<C / 4, 256, 0, stream>>>(cb, cn);
  dist_kernel<<<B / BM, 256, 0, stream>>>(feat, cbhi, cblo, cn, Hrow, amin,
                                          flagged, flagCount, C);
  refine_kernel<<<128, 256, 0, stream>>>(feat, cb, amin, flagged, flagCount, C);
  gather_kernel<<<B / 64, 256, 0, stream>>>(feat, cb, amin, Hrow, out, lossAcc, hAcc);
  finalize_kernel<<<1, 64, 0, stream>>>(lossAcc, hAcc, out,
                                        (size_t)B * DDIM,
                                        1.0f / ((float)B * (float)DDIM),
                                        1.0f / (float)B);
}

// Round 6
// 803.539 us; speedup vs baseline: 18.6501x; 1.9530x over previous
//
#include <hip/hip_runtime.h>
#include <math.h>

// VQ codebook: B=32768 x C=8192, D=256.
// Round 6: refine_kernel restructured. Old: one code per WAVE with a 6-step
// fp64 shuffle reduce inside every code's dep chain (982 us, VALUBusy 2.4%).
// New: one code per THREAD (32 codes/thread), feature row staged as fp64 in
// LDS, block-wide (min,idx) LDS tree once per row. ~80 us expected.
// dist (MFMA bf16 hi/lo) unchanged from round 5.

#define DDIM 256
#define BM 128
#define BN 128
#define LOG2E 1.44269504f
#define NEG2L (-2.88539008f)
#define LN2 0.69314718f
#define MARGIN_Y 0.0288539f   // 0.02 * log2e

typedef short bf16x8 __attribute__((ext_vector_type(8)));
typedef unsigned short ushort8 __attribute__((ext_vector_type(8)));
typedef float f32x4 __attribute__((ext_vector_type(4)));

__device__ __forceinline__ unsigned short f2bf(float f) {
  unsigned u = __float_as_uint(f);
  return (unsigned short)((u + 0x7FFF + ((u >> 16) & 1)) >> 16);
}
__device__ __forceinline__ float bf2f(unsigned short h) {
  return __uint_as_float(((unsigned)h) << 16);
}
__device__ __forceinline__ void gload_lds16(const void* g, void* l) {
  __builtin_amdgcn_global_load_lds(
      (const __attribute__((address_space(1))) void*)g,
      (__attribute__((address_space(3))) void*)l, 16, 0, 0);
}

__global__ void init_kernel(int* flagCount, float* lossAcc, float* hAcc) {
  if (threadIdx.x == 0) { *flagCount = 0; *lossAcc = 0.f; *hAcc = 0.f; }
}

// elementwise fp32 -> bf16 hi + bf16 lo residual (8 elems/thread)
__global__ void cvt_cb_kernel(const float* __restrict__ cb,
                              unsigned short* __restrict__ hi,
                              unsigned short* __restrict__ lo) {
  const size_t base = ((size_t)blockIdx.x * 256 + threadIdx.x) * 8;
  const float4 f0 = *reinterpret_cast<const float4*>(cb + base);
  const float4 f1 = *reinterpret_cast<const float4*>(cb + base + 4);
  float fv[8] = {f0.x, f0.y, f0.z, f0.w, f1.x, f1.y, f1.z, f1.w};
  ushort8 h, l;
  #pragma unroll
  for (int e = 0; e < 8; ++e) {
    unsigned short hh = f2bf(fv[e]);
    h[e] = hh;
    l[e] = f2bf(fv[e] - bf2f(hh));
  }
  *reinterpret_cast<ushort8*>(hi + base) = h;
  *reinterpret_cast<ushort8*>(lo + base) = l;
}

// one wave per codebook row: cn[c] = sum(cb[c,:]^2)  (exact fp32 source)
__global__ void cn_kernel(const float* __restrict__ cb, float* __restrict__ cn) {
  const int lane = threadIdx.x & 63;
  const int wave = threadIdx.x >> 6;
  const int c = blockIdx.x * 4 + wave;
  const float4 v = *reinterpret_cast<const float4*>(cb + (size_t)c * DDIM + lane * 4);
  float s = v.x * v.x + v.y * v.y + v.z * v.z + v.w * v.w;
  #pragma unroll
  for (int off = 1; off < 64; off <<= 1) s += __shfl_xor(s, off, 64);
  if (lane == 0) cn[c] = s;
}

__launch_bounds__(256, 1)
__global__ void dist_kernel(const float* __restrict__ feat,
                            const unsigned short* __restrict__ cbhi,
                            const unsigned short* __restrict__ cblo,
                            const float* __restrict__ cn,
                            float* __restrict__ Hrow,
                            int* __restrict__ aminArr,
                            int* __restrict__ flagged,
                            int* __restrict__ flagCount,
                            int C) {
  __shared__ unsigned short sFhi[BM * DDIM];  // 65536 B, rows of 512 B, swizzled
  __shared__ unsigned short sFlo[BM * DDIM];  // 65536 B
  __shared__ unsigned short sChi[BN * 64];    // 16384 B, rows of 128 B, swizzled
  __shared__ unsigned short sClo[BN * 64];    // 16384 B   (total 163840 B)
  const int tid = threadIdx.x;
  const int lane = tid & 63;
  const int w = tid >> 6;        // wave 0..3 -> rows w*32..w*32+31
  const int lr = lane & 15;      // row-in-tile (A) / col-in-tile (B)
  const int g = lane >> 4;       // k-group (4 x 8 elems = K32 frag)
  const size_t rowBase = (size_t)blockIdx.x * BM;

  char* sFhiB = (char*)sFhi; char* sFloB = (char*)sFlo;
  char* sChiB = (char*)sChi; char* sCloB = (char*)sClo;

  // ---- stage features: fp32 -> bf16 hi/lo, swizzled rows of 512 B ----
  #pragma unroll 1
  for (int it = 0; it < 16; ++it) {
    int idx8 = tid + it * 256;        // float8 granule, 4096 total
    int row = idx8 >> 5;              // 32 granules per 256-f row
    int k8 = idx8 & 31;
    const float* fp = feat + (rowBase + row) * DDIM + k8 * 8;
    const float4 f0 = *reinterpret_cast<const float4*>(fp);
    const float4 f1 = *reinterpret_cast<const float4*>(fp + 4);
    float fv[8] = {f0.x, f0.y, f0.z, f0.w, f1.x, f1.y, f1.z, f1.w};
    ushort8 h, l;
    #pragma unroll
    for (int e = 0; e < 8; ++e) {
      unsigned short hh = f2bf(fv[e]);
      h[e] = hh;
      l[e] = f2bf(fv[e] - bf2f(hh));
    }
    int off = (k8 * 16) ^ ((row & 7) << 4);
    *reinterpret_cast<ushort8*>(sFhiB + row * 512 + off) = h;
    *reinterpret_cast<ushort8*>(sFloB + row * 512 + off) = l;
  }

  // per-lane state: 8 rows (mt 0..1 x r 0..3), 8 cols (nt 0..7, col=nt*16+lr)
  float dminY[8], dmin2Y[8], mmY[8], ss[8], vv[8];
  int am[8];
  #pragma unroll
  for (int i = 0; i < 8; ++i) {
    dminY[i] = INFINITY; dmin2Y[i] = INFINITY;
    mmY[i] = 1e9f; ss[i] = 0.f; vv[i] = 0.f; am[i] = 0;
  }

  const int nchunk = C / BN;
  #pragma unroll 1
  for (int ch = 0; ch < nchunk; ++ch) {
    const int cBase = ch * BN;
    float cnL[8];
    #pragma unroll
    for (int nt = 0; nt < 8; ++nt)
      cnL[nt] = cn[cBase + nt * 16 + lr] * LOG2E;

    f32x4 acc[2][8];
    #pragma unroll
    for (int mt = 0; mt < 2; ++mt)
      #pragma unroll
      for (int nt = 0; nt < 8; ++nt)
        acc[mt][nt] = (f32x4){0.f, 0.f, 0.f, 0.f};

    #pragma unroll 1
    for (int kt = 0; kt < 4; ++kt) {   // K-tiles of 64
      __syncthreads();   // previous sC consumers done (covers sF stage @first)
      // stage sC[kt]: wave w fills bytes [w*4096, w*4096+4096) of hi and lo.
      // Linear LDS dest (base + lane*16), pre-swizzled global source.
      #pragma unroll
      for (int it = 0; it < 4; ++it) {
        int L = w * 4096 + it * 1024 + lane * 16;
        int code = L >> 7;            // 128 B per code row
        int kb = L & 127;
        size_t srcOff = (((size_t)(cBase + code)) << 9) + (size_t)kt * 128 +
                        (kb ^ ((code & 7) << 4));
        gload_lds16((const char*)cbhi + srcOff, sChiB + w * 4096 + it * 1024);
        gload_lds16((const char*)cblo + srcOff, sCloB + w * 4096 + it * 1024);
      }
      __syncthreads();   // staged data visible (barrier drains vmcnt)

      #pragma unroll
      for (int ks = 0; ks < 2; ++ks) {  // two K=32 MFMA steps
        bf16x8 ahi[2], alo[2];
        #pragma unroll
        for (int mt = 0; mt < 2; ++mt) {
          int row = w * 32 + mt * 16 + lr;
          int off = (kt * 128 + ks * 64 + g * 16) ^ ((row & 7) << 4);
          ahi[mt] = *reinterpret_cast<const bf16x8*>(sFhiB + row * 512 + off);
          alo[mt] = *reinterpret_cast<const bf16x8*>(sFloB + row * 512 + off);
        }
        #pragma unroll
        for (int nt = 0; nt < 8; ++nt) {
          int code = nt * 16 + lr;
          int boff = (ks * 64 + g * 16) ^ ((code & 7) << 4);
          bf16x8 bhi = *reinterpret_cast<const bf16x8*>(sChiB + code * 128 + boff);
          bf16x8 blo = *reinterpret_cast<const bf16x8*>(sCloB + code * 128 + boff);
          #pragma unroll
          for (int mt = 0; mt < 2; ++mt) {
            acc[mt][nt] = __builtin_amdgcn_mfma_f32_16x16x32_bf16(ahi[mt], bhi, acc[mt][nt], 0, 0, 0);
            acc[mt][nt] = __builtin_amdgcn_mfma_f32_16x16x32_bf16(alo[mt], bhi, acc[mt][nt], 0, 0, 0);
            acc[mt][nt] = __builtin_amdgcn_mfma_f32_16x16x32_bf16(ahi[mt], blo, acc[mt][nt], 0, 0, 0);
          }
        }
      }
    }

    // ---- online epilogue in log2 units: y = dt*log2e = fma(dot, -2L, cnL) ----
    #pragma unroll
    for (int mt = 0; mt < 2; ++mt) {
      #pragma unroll
      for (int r = 0; r < 4; ++r) {
        const int s = mt * 4 + r;
        float y[8];
        #pragma unroll
        for (int nt = 0; nt < 8; ++nt)
          y[nt] = fmaf(acc[mt][nt][r], NEG2L, cnL[nt]);
        float m8 = fminf(fminf(fminf(y[0], y[1]), fminf(y[2], y[3])),
                         fminf(fminf(y[4], y[5]), fminf(y[6], y[7])));
        float nm = fminf(mmY[s], m8);
        float scl = __builtin_amdgcn_exp2f(nm - mmY[s]);  // ==1 when no update
        ss[s] *= scl; vv[s] *= scl; mmY[s] = nm;
        #pragma unroll
        for (int nt = 0; nt < 8; ++nt) {
          float e = __builtin_amdgcn_exp2f(nm - y[nt]);
          ss[s] += e;
          vv[s] = fmaf(y[nt], e, vv[s]);
          int cidx = cBase + nt * 16 + lr;
          bool lt = y[nt] < dminY[s];
          dmin2Y[s] = fminf(dmin2Y[s], fmaxf(y[nt], dminY[s]));
          am[s] = lt ? cidx : am[s];
          dminY[s] = fminf(dminY[s], y[nt]);
        }
      }
    }
  }

  // ---- butterfly-merge across the 16 lanes of each k-group (bits 0..3) ----
  #pragma unroll
  for (int i = 0; i < 8; ++i) {
    #pragma unroll
    for (int off = 1; off <= 8; off <<= 1) {
      float od = __shfl_xor(dminY[i], off, 64);
      float od2 = __shfl_xor(dmin2Y[i], off, 64);
      int oa = __shfl_xor(am[i], off, 64);
      float om = __shfl_xor(mmY[i], off, 64);
      float os = __shfl_xor(ss[i], off, 64);
      float ov = __shfl_xor(vv[i], off, 64);
      float hi = fmaxf(dminY[i], od);
      dmin2Y[i] = fminf(fminf(dmin2Y[i], od2), hi);
      am[i] = (od < dminY[i]) ? oa : ((od == dminY[i]) ? (oa < am[i] ? oa : am[i]) : am[i]);
      dminY[i] = fminf(dminY[i], od);
      float nm = fminf(mmY[i], om);
      float sa = __builtin_amdgcn_exp2f(nm - mmY[i]);
      float sb = __builtin_amdgcn_exp2f(nm - om);
      ss[i] = ss[i] * sa + os * sb;
      vv[i] = vv[i] * sa + ov * sb;
      mmY[i] = nm;
    }
    if (lr == 0) {
      size_t row = rowBase + w * 32 + (i >> 2) * 16 + 4 * g + (i & 3);
      Hrow[row] = logf(ss[i]) + LN2 * (vv[i] / ss[i] - mmY[i]);
      aminArr[row] = am[i];
      if (dmin2Y[i] - dminY[i] < MARGIN_Y) {
        int slot = atomicAdd(flagCount, 1);
        flagged[slot] = (int)row;
      }
    }
  }
}

// exact fp64 argmin for flagged (near-tie) rows, from original fp32 data.
// One CODE per THREAD (32 codes/thread), feature row staged as fp64 in LDS,
// block-wide (min,idx) tree once per row. No per-code reduction.
__launch_bounds__(256)
__global__ void refine_kernel(const float* __restrict__ feat,
                              const float* __restrict__ cb,
                              int* __restrict__ aminArr,
                              const int* __restrict__ flagged,
                              const int* __restrict__ flagCount,
                              int C) {
  __shared__ double sRow[DDIM];   // 2 KB
  __shared__ double sMin[256];    // 2 KB
  __shared__ int sIdx[256];       // 1 KB
  const int tid = threadIdx.x;
  const int nf = *flagCount;
  for (int f = blockIdx.x; f < nf; f += gridDim.x) {
    const int row = flagged[f];
    sRow[tid] = (double)feat[(size_t)row * DDIM + tid];
    __syncthreads();
    double lmin = 1e300; int lidx = 0;
    #pragma unroll 1
    for (int c = tid; c < C; c += 256) {
      const float* cp = cb + (size_t)c * DDIM;
      double s0 = 0.0, s1 = 0.0;
      #pragma unroll 4
      for (int d = 0; d < DDIM; d += 8) {
        const float4 a = *reinterpret_cast<const float4*>(cp + d);
        const float4 b = *reinterpret_cast<const float4*>(cp + d + 4);
        double d0 = sRow[d]     - (double)a.x;
        double d1 = sRow[d + 1] - (double)a.y;
        double d2 = sRow[d + 2] - (double)a.z;
        double d3 = sRow[d + 3] - (double)a.w;
        double e0 = sRow[d + 4] - (double)b.x;
        double e1 = sRow[d + 5] - (double)b.y;
        double e2 = sRow[d + 6] - (double)b.z;
        double e3 = sRow[d + 7] - (double)b.w;
        s0 += d0 * d0 + d1 * d1 + d2 * d2 + d3 * d3;
        s1 += e0 * e0 + e1 * e1 + e2 * e2 + e3 * e3;
      }
      const double s = s0 + s1;
      if (s < lmin) { lmin = s; lidx = c; }  // ascending c: first-min kept
    }
    sMin[tid] = lmin; sIdx[tid] = lidx;
    __syncthreads();
    #pragma unroll
    for (int stride = 128; stride > 0; stride >>= 1) {
      if (tid < stride) {
        const double o = sMin[tid + stride]; const int oi = sIdx[tid + stride];
        if (o < sMin[tid] || (o == sMin[tid] && oi < sIdx[tid])) {
          sMin[tid] = o; sIdx[tid] = oi;
        }
      }
      __syncthreads();
    }
    if (tid == 0) aminArr[row] = sIdx[0];
    __syncthreads();
  }
}

__launch_bounds__(256)
__global__ void gather_kernel(const float* __restrict__ feat,
                              const float* __restrict__ cb,
                              const int* __restrict__ aminArr,
                              const float* __restrict__ Hrow,
                              float* __restrict__ out,
                              float* lossAcc, float* hAcc) {
  const int tid = threadIdx.x;
  const int lane = tid & 63;
  const int wave = tid >> 6;
  const size_t base = (size_t)blockIdx.x * 64;
  float lsum = 0.f;
  #pragma unroll 1
  for (int r = wave; r < 64; r += 4) {
    const size_t row = base + r;
    const int q = aminArr[row];
    const float4 cv = *reinterpret_cast<const float4*>(cb + (size_t)q * DDIM + lane * 4);
    const float4 fv = *reinterpret_cast<const float4*>(feat + row * DDIM + lane * 4);
    *reinterpret_cast<float4*>(out + row * DDIM + lane * 4) = cv;
    const float dx = cv.x - fv.x, dy = cv.y - fv.y, dz = cv.z - fv.z, dw = cv.w - fv.w;
    lsum += dx * dx + dy * dy + dz * dz + dw * dw;
  }
  #pragma unroll
  for (int off = 1; off < 64; off <<= 1) lsum += __shfl_xor(lsum, off, 64);
  __shared__ float wsum[4];
  if (lane == 0) wsum[wave] = lsum;
  __syncthreads();
  if (tid == 0) atomicAdd(lossAcc, wsum[0] + wsum[1] + wsum[2] + wsum[3]);
  if (wave == 0) {
    float h = Hrow[base + lane];
    #pragma unroll
    for (int off = 1; off < 64; off <<= 1) h += __shfl_xor(h, off, 64);
    if (lane == 0) atomicAdd(hAcc, h);
  }
}

__global__ void finalize_kernel(const float* lossAcc, const float* hAcc,
                                float* out, size_t M, float invBD, float invB) {
  if (threadIdx.x == 0) {
    float L = *lossAcc * invBD;
    out[M] = L;
    out[M + 1] = L;
    out[M + 2] = *hAcc * invB;
  }
}

extern "C" void kernel_launch(void* const* d_in, const int* in_sizes, int n_in,
                              void* d_out, int out_size, void* d_ws, size_t ws_size,
                              hipStream_t stream) {
  (void)n_in; (void)out_size; (void)ws_size;
  const float* feat = (const float*)d_in[0];
  const float* cb   = (const float*)d_in[1];
  const int B = in_sizes[0] / DDIM;  // 32768
  const int C = in_sizes[1] / DDIM;  // 8192
  float* out = (float*)d_out;

  unsigned short* cbhi = (unsigned short*)d_ws;          // C*DDIM bf16
  unsigned short* cblo = cbhi + (size_t)C * DDIM;        // C*DDIM bf16
  float* cn      = (float*)(cblo + (size_t)C * DDIM);    // C
  float* Hrow    = cn + C;                               // B
  int*   amin    = (int*)(Hrow + B);                     // B
  int*   flagged = amin + B;                             // B
  int*   flagCount = flagged + B;                        // 1
  float* lossAcc = (float*)(flagCount + 1);              // 1
  float* hAcc    = lossAcc + 1;                          // 1

  init_kernel<<<1, 64, 0, stream>>>(flagCount, lossAcc, hAcc);
  cvt_cb_kernel<<<(C * DDIM) / (256 * 8), 256, 0, stream>>>(cb, cbhi, cblo);
  cn_kernel<<<C / 4, 256, 0, stream>>>(cb, cn);
  dist_kernel<<<B / BM, 256, 0, stream>>>(feat, cbhi, cblo, cn, Hrow, amin,
                                          flagged, flagCount, C);
  refine_kernel<<<256, 256, 0, stream>>>(feat, cb, amin, flagged, flagCount, C);
  gather_kernel<<<B / 64, 256, 0, stream>>>(feat, cb, amin, Hrow, out, lossAcc, hAcc);
  finalize_kernel<<<1, 64, 0, stream>>>(lossAcc, hAcc, out,
                                        (size_t)B * DDIM,
                                        1.0f / ((float)B * (float)DDIM),
                                        1.0f / (float)B);
}

// Round 7
// 708.147 us; speedup vs baseline: 21.1624x; 1.1347x over previous
//
#include <hip/hip_runtime.h>
#include <math.h>

// VQ codebook: B=32768 x C=8192, D=256.
// Round 7: dist pipeline rebuilt: (1) double-buffered sC (KT=32) so
// global_load_lds latency hides under MFMA (old code drained vmcnt(0) right
// after issue -> ~200us exposed); (2) 2x2 wave grid (64x64 per wave) cuts LDS
// reads 640->512 b128/chunk/CU; (3) all LDS addresses are base-VGPR +
// compile-time immediate (swizzle folded into per-thread bases; zero per-read
// VALU). LDS = sF 128 KiB (interleaved hi/lo, XOR-swizzled) + sC 2x16 KiB
// (code-pair swizzle, 2-way free) = 163840 B exactly. 1 block/CU ->
// 512 VGPR/wave budget, no spill.

#define DDIM 256
#define BM 128
#define BN 128
#define LOG2E 1.44269504f
#define NEG2L (-2.88539008f)
#define LN2 0.69314718f
#define MARGIN_Y 0.0288539f   // 0.02 * log2e
#define SC0 131072            // sC byte offset in smem

typedef short bf16x8 __attribute__((ext_vector_type(8)));
typedef unsigned short ushort8 __attribute__((ext_vector_type(8)));
typedef float f32x4 __attribute__((ext_vector_type(4)));

__device__ __forceinline__ unsigned short f2bf(float f) {
  unsigned u = __float_as_uint(f);
  return (unsigned short)((u + 0x7FFF + ((u >> 16) & 1)) >> 16);
}
__device__ __forceinline__ float bf2f(unsigned short h) {
  return __uint_as_float(((unsigned)h) << 16);
}
__device__ __forceinline__ void gload_lds16(const void* g, void* l) {
  __builtin_amdgcn_global_load_lds(
      (const __attribute__((address_space(1))) void*)g,
      (__attribute__((address_space(3))) void*)l, 16, 0, 0);
}

__global__ void init_kernel(int* flagCount, float* lossAcc, float* hAcc) {
  if (threadIdx.x == 0) { *flagCount = 0; *lossAcc = 0.f; *hAcc = 0.f; }
}

// elementwise fp32 -> bf16 hi + bf16 lo residual (8 elems/thread)
__global__ void cvt_cb_kernel(const float* __restrict__ cb,
                              unsigned short* __restrict__ hi,
                              unsigned short* __restrict__ lo) {
  const size_t base = ((size_t)blockIdx.x * 256 + threadIdx.x) * 8;
  const float4 f0 = *reinterpret_cast<const float4*>(cb + base);
  const float4 f1 = *reinterpret_cast<const float4*>(cb + base + 4);
  float fv[8] = {f0.x, f0.y, f0.z, f0.w, f1.x, f1.y, f1.z, f1.w};
  ushort8 h, l;
  #pragma unroll
  for (int e = 0; e < 8; ++e) {
    unsigned short hh = f2bf(fv[e]);
    h[e] = hh;
    l[e] = f2bf(fv[e] - bf2f(hh));
  }
  *reinterpret_cast<ushort8*>(hi + base) = h;
  *reinterpret_cast<ushort8*>(lo + base) = l;
}

// one wave per codebook row: cn[c] = sum(cb[c,:]^2)  (exact fp32 source)
__global__ void cn_kernel(const float* __restrict__ cb, float* __restrict__ cn) {
  const int lane = threadIdx.x & 63;
  const int wave = threadIdx.x >> 6;
  const int c = blockIdx.x * 4 + wave;
  const float4 v = *reinterpret_cast<const float4*>(cb + (size_t)c * DDIM + lane * 4);
  float s = v.x * v.x + v.y * v.y + v.z * v.z + v.w * v.w;
  #pragma unroll
  for (int off = 1; off < 64; off <<= 1) s += __shfl_xor(s, off, 64);
  if (lane == 0) cn[c] = s;
}

// ---- dist: fused 3-term bf16 MFMA GEMM + online argmin/min2 + entropy ----
__launch_bounds__(256, 1)
__global__ void dist_kernel(const float* __restrict__ feat,
                            const unsigned short* __restrict__ cbhi,
                            const unsigned short* __restrict__ cblo,
                            const float* __restrict__ cn,
                            float* __restrict__ Hrow,
                            int* __restrict__ aminArr,
                            int* __restrict__ flagged,
                            int* __restrict__ flagCount,
                            int C) {
  __shared__ __align__(1024) char smem[163840];
  const int tid = threadIdx.x;
  const int lane = tid & 63;
  const int w = tid >> 6;        // wave 0..3
  const int wr = w >> 1;         // wave-row: rows wr*64 .. +63
  const int wc = w & 1;          // wave-col: cols wc*64 .. +63
  const int lr = lane & 15;
  const int g = lane >> 4;
  const size_t rowBase = (size_t)blockIdx.x * BM;

  // ---- A base pointers: addr = base[par][mt] + (kt>>1)*128 (+512 for lo) ----
  const int e = lr & 7;
  const int Q = ((g ^ (e & 3)) << 4) + ((e >> 2) << 6);
  const char* baseAe[4]; const char* baseAo[4];
  #pragma unroll
  for (int mt = 0; mt < 4; ++mt) {
    int row = wr * 64 + mt * 16 + lr;
    baseAe[mt] = smem + row * 1024 + Q;
    baseAo[mt] = smem + row * 1024 + (Q ^ 64);
  }
  // ---- B base pointers: addr = baseB{0,1} + nt*1024 (+8192 for lo) ----
  const int vB = (((lane & 1) * 4 + g) ^ ((lr >> 1) & 7)) * 16;
  const char* baseB0 = smem + SC0 + wc * 4096 + (lr >> 1) * 128 + vB;
  const char* baseB1 = baseB0 + 16384;

  // ---- B staging source pointers (per-thread, advance by constants) ----
  int c_[2], gp_[2];
  #pragma unroll
  for (int it = 0; it < 2; ++it) {
    int L = w * 2048 + it * 1024 + lane * 16;
    int rowp = L >> 7;
    int vlog = ((L >> 4) & 7) ^ (rowp & 7);
    c_[it] = 2 * rowp + (vlog >> 2);
    gp_[it] = vlog & 3;
  }
  const char* pH0 = (const char*)cbhi + c_[0] * 512 + gp_[0] * 16;
  const char* pH1 = (const char*)cbhi + c_[1] * 512 + gp_[1] * 16;
  const char* pL0 = (const char*)cblo + c_[0] * 512 + gp_[0] * 16;
  const char* pL1 = (const char*)cblo + c_[1] * 512 + gp_[1] * 16;

#define STAGE(BUF, ADV) do { \
    char* d_ = smem + SC0 + (BUF) * 16384 + w * 2048; \
    gload_lds16(pH0, d_); \
    gload_lds16(pH1, d_ + 1024); \
    gload_lds16(pL0, d_ + 8192); \
    gload_lds16(pL1, d_ + 9216); \
    pH0 += (ADV); pH1 += (ADV); pL0 += (ADV); pL1 += (ADV); \
  } while (0)

  // prologue: stage phase 0 (chunk 0, kt 0) into buf 0; stage sF; barrier
  STAGE(0, 64);

  // ---- stage features: fp32 -> bf16 hi/lo, interleaved swizzled rows ----
  #pragma unroll 1
  for (int it = 0; it < 16; ++it) {
    int idx8 = tid + it * 256;        // float8 granule, 4096 total
    int row = idx8 >> 5;
    int k8 = idx8 & 31;
    const float* fp = feat + (rowBase + row) * DDIM + k8 * 8;
    const float4 f0 = *reinterpret_cast<const float4*>(fp);
    const float4 f1 = *reinterpret_cast<const float4*>(fp + 4);
    float fv[8] = {f0.x, f0.y, f0.z, f0.w, f1.x, f1.y, f1.z, f1.w};
    ushort8 h, l;
    #pragma unroll
    for (int ee = 0; ee < 8; ++ee) {
      unsigned short hh = f2bf(fv[ee]);
      h[ee] = hh;
      l[ee] = f2bf(fv[ee] - bf2f(hh));
    }
    int off = row * 1024 + ((k8 ^ (row & 7)) << 4);
    *reinterpret_cast<ushort8*>(smem + off) = h;
    *reinterpret_cast<ushort8*>(smem + off + 512) = l;
  }
  __syncthreads();   // sF visible; phase-0 sC staged (vmcnt drained)

  // per-lane state: 16 row-states (mt*4 + r), 4 cols each (nt*16 + lr)
  float dminY[16], dmin2Y[16], mmY[16], ss[16], vv[16];
  int am[16];
  #pragma unroll
  for (int i = 0; i < 16; ++i) {
    dminY[i] = INFINITY; dmin2Y[i] = INFINITY;
    mmY[i] = 1e9f; ss[i] = 0.f; vv[i] = 0.f; am[i] = 0;
  }

  f32x4 acc[4][4];

#define PHASE(KT) do { \
    STAGE(((KT) + 1) & 1, ((KT) == 6) ? 65088 : 64); \
    bf16x8 ah[4], al[4]; \
    _Pragma("unroll") \
    for (int mt = 0; mt < 4; ++mt) { \
      const char* ab_ = (((KT) & 1) ? baseAo[mt] : baseAe[mt]) + ((KT) >> 1) * 128; \
      ah[mt] = *reinterpret_cast<const bf16x8*>(ab_); \
      al[mt] = *reinterpret_cast<const bf16x8*>(ab_ + 512); \
    } \
    _Pragma("unroll") \
    for (int nt = 0; nt < 4; ++nt) { \
      const char* bb_ = (((KT) & 1) ? baseB1 : baseB0) + nt * 1024; \
      bf16x8 bh = *reinterpret_cast<const bf16x8*>(bb_); \
      bf16x8 bl = *reinterpret_cast<const bf16x8*>(bb_ + 8192); \
      _Pragma("unroll") \
      for (int mt = 0; mt < 4; ++mt) { \
        acc[mt][nt] = __builtin_amdgcn_mfma_f32_16x16x32_bf16(ah[mt], bh, acc[mt][nt], 0, 0, 0); \
        acc[mt][nt] = __builtin_amdgcn_mfma_f32_16x16x32_bf16(al[mt], bh, acc[mt][nt], 0, 0, 0); \
        acc[mt][nt] = __builtin_amdgcn_mfma_f32_16x16x32_bf16(ah[mt], bl, acc[mt][nt], 0, 0, 0); \
      } \
    } \
    __syncthreads(); \
  } while (0)

  const int nchunk = C / BN;
  #pragma unroll 1
  for (int ch = 0; ch < nchunk; ++ch) {
    const int cBase = ch * BN;
    float cnL[4];
    #pragma unroll
    for (int nt = 0; nt < 4; ++nt)
      cnL[nt] = cn[cBase + wc * 64 + nt * 16 + lr] * LOG2E;
    #pragma unroll
    for (int mt = 0; mt < 4; ++mt)
      #pragma unroll
      for (int nt = 0; nt < 4; ++nt)
        acc[mt][nt] = (f32x4){0.f, 0.f, 0.f, 0.f};

    PHASE(0); PHASE(1); PHASE(2); PHASE(3);
    PHASE(4); PHASE(5); PHASE(6); PHASE(7);

    // ---- online epilogue in log2 units ----
    #pragma unroll
    for (int mt = 0; mt < 4; ++mt) {
      #pragma unroll
      for (int r = 0; r < 4; ++r) {
        const int s = mt * 4 + r;
        float y[4];
        #pragma unroll
        for (int nt = 0; nt < 4; ++nt)
          y[nt] = fmaf(acc[mt][nt][r], NEG2L, cnL[nt]);
        float m4 = fminf(fminf(y[0], y[1]), fminf(y[2], y[3]));
        float nm = fminf(mmY[s], m4);
        float scl = __builtin_amdgcn_exp2f(nm - mmY[s]);
        ss[s] *= scl; vv[s] *= scl; mmY[s] = nm;
        #pragma unroll
        for (int nt = 0; nt < 4; ++nt) {
          float ev = __builtin_amdgcn_exp2f(nm - y[nt]);
          ss[s] += ev;
          vv[s] = fmaf(y[nt], ev, vv[s]);
          int cidx = cBase + wc * 64 + nt * 16 + lr;
          bool lt = y[nt] < dminY[s];
          dmin2Y[s] = fminf(dmin2Y[s], fmaxf(y[nt], dminY[s]));
          am[s] = lt ? cidx : am[s];
          dminY[s] = fminf(dminY[s], y[nt]);
        }
      }
    }
  }

  // ---- butterfly-merge across the 16 lanes of each k-group ----
  #pragma unroll
  for (int i = 0; i < 16; ++i) {
    #pragma unroll
    for (int off = 1; off <= 8; off <<= 1) {
      float od = __shfl_xor(dminY[i], off, 64);
      float od2 = __shfl_xor(dmin2Y[i], off, 64);
      int oa = __shfl_xor(am[i], off, 64);
      float om = __shfl_xor(mmY[i], off, 64);
      float os = __shfl_xor(ss[i], off, 64);
      float ov = __shfl_xor(vv[i], off, 64);
      float hi = fmaxf(dminY[i], od);
      dmin2Y[i] = fminf(fminf(dmin2Y[i], od2), hi);
      am[i] = (od < dminY[i]) ? oa : ((od == dminY[i]) ? (oa < am[i] ? oa : am[i]) : am[i]);
      dminY[i] = fminf(dminY[i], od);
      float nm = fminf(mmY[i], om);
      float sa = __builtin_amdgcn_exp2f(nm - mmY[i]);
      float sb = __builtin_amdgcn_exp2f(nm - om);
      ss[i] = ss[i] * sa + os * sb;
      vv[i] = vv[i] * sa + ov * sb;
      mmY[i] = nm;
    }
    // lane lr==0 of each g-group stages its half-row state to LDS
    if (lr == 0) {
      int rowl = wr * 64 + (i >> 2) * 16 + g * 4 + (i & 3);
      float* mb = reinterpret_cast<float*>(smem) + (size_t)(wc * 128 + rowl) * 8;
      mb[0] = dminY[i]; mb[1] = dmin2Y[i]; mb[2] = __int_as_float(am[i]);
      mb[3] = mmY[i];   mb[4] = ss[i];     mb[5] = vv[i];
    }
  }
  __syncthreads();

  // ---- final cross-half merge (cols 0-63 vs 64-127 per chunk) ----
  if (tid < 128) {
    const float* a = reinterpret_cast<const float*>(smem) + (size_t)tid * 8;
    const float* b = a + 128 * 8;
    float da = a[0], d2a = a[1], ma = a[3], sa_ = a[4], va = a[5];
    int   aa = __float_as_int(a[2]);
    float db = b[0], d2b = b[1], mb_ = b[3], sb_ = b[4], vb = b[5];
    int   ab = __float_as_int(b[2]);
    float dmin = fminf(da, db);
    float dmin2 = fminf(fminf(d2a, d2b), fmaxf(da, db));
    int amF = (da < db) ? aa : ((db < da) ? ab : (aa < ab ? aa : ab));
    float nm = fminf(ma, mb_);
    float ea = __builtin_amdgcn_exp2f(nm - ma);
    float eb = __builtin_amdgcn_exp2f(nm - mb_);
    float S = sa_ * ea + sb_ * eb;
    float V = va * ea + vb * eb;
    size_t row = rowBase + tid;
    Hrow[row] = logf(S) + LN2 * (V / S - nm);
    aminArr[row] = amF;
    if (dmin2 - dmin < MARGIN_Y) {
      int slot = atomicAdd(flagCount, 1);
      flagged[slot] = (int)row;
    }
  }
#undef PHASE
#undef STAGE
}

// exact fp64 argmin for flagged (near-tie) rows, one code per thread
__launch_bounds__(256)
__global__ void refine_kernel(const float* __restrict__ feat,
                              const float* __restrict__ cb,
                              int* __restrict__ aminArr,
                              const int* __restrict__ flagged,
                              const int* __restrict__ flagCount,
                              int C) {
  __shared__ double sRow[DDIM];
  __shared__ double sMin[256];
  __shared__ int sIdx[256];
  const int tid = threadIdx.x;
  const int nf = *flagCount;
  for (int f = blockIdx.x; f < nf; f += gridDim.x) {
    const int row = flagged[f];
    sRow[tid] = (double)feat[(size_t)row * DDIM + tid];
    __syncthreads();
    double lmin = 1e300; int lidx = 0;
    #pragma unroll 1
    for (int c = tid; c < C; c += 256) {
      const float* cp = cb + (size_t)c * DDIM;
      double s0 = 0.0, s1 = 0.0;
      #pragma unroll 4
      for (int d = 0; d < DDIM; d += 8) {
        const float4 a = *reinterpret_cast<const float4*>(cp + d);
        const float4 b = *reinterpret_cast<const float4*>(cp + d + 4);
        double d0 = sRow[d]     - (double)a.x;
        double d1 = sRow[d + 1] - (double)a.y;
        double d2 = sRow[d + 2] - (double)a.z;
        double d3 = sRow[d + 3] - (double)a.w;
        double e0 = sRow[d + 4] - (double)b.x;
        double e1 = sRow[d + 5] - (double)b.y;
        double e2 = sRow[d + 6] - (double)b.z;
        double e3 = sRow[d + 7] - (double)b.w;
        s0 += d0 * d0 + d1 * d1 + d2 * d2 + d3 * d3;
        s1 += e0 * e0 + e1 * e1 + e2 * e2 + e3 * e3;
      }
      const double s = s0 + s1;
      if (s < lmin) { lmin = s; lidx = c; }
    }
    sMin[tid] = lmin; sIdx[tid] = lidx;
    __syncthreads();
    #pragma unroll
    for (int stride = 128; stride > 0; stride >>= 1) {
      if (tid < stride) {
        const double o = sMin[tid + stride]; const int oi = sIdx[tid + stride];
        if (o < sMin[tid] || (o == sMin[tid] && oi < sIdx[tid])) {
          sMin[tid] = o; sIdx[tid] = oi;
        }
      }
      __syncthreads();
    }
    if (tid == 0) aminArr[row] = sIdx[0];
    __syncthreads();
  }
}

__launch_bounds__(256)
__global__ void gather_kernel(const float* __restrict__ feat,
                              const float* __restrict__ cb,
                              const int* __restrict__ aminArr,
                              const float* __restrict__ Hrow,
                              float* __restrict__ out,
                              float* lossAcc, float* hAcc) {
  const int tid = threadIdx.x;
  const int lane = tid & 63;
  const int wave = tid >> 6;
  const size_t base = (size_t)blockIdx.x * 64;
  float lsum = 0.f;
  #pragma unroll 1
  for (int r = wave; r < 64; r += 4) {
    const size_t row = base + r;
    const int q = aminArr[row];
    const float4 cv = *reinterpret_cast<const float4*>(cb + (size_t)q * DDIM + lane * 4);
    const float4 fv = *reinterpret_cast<const float4*>(feat + row * DDIM + lane * 4);
    *reinterpret_cast<float4*>(out + row * DDIM + lane * 4) = cv;
    const float dx = cv.x - fv.x, dy = cv.y - fv.y, dz = cv.z - fv.z, dw = cv.w - fv.w;
    lsum += dx * dx + dy * dy + dz * dz + dw * dw;
  }
  #pragma unroll
  for (int off = 1; off < 64; off <<= 1) lsum += __shfl_xor(lsum, off, 64);
  __shared__ float wsum[4];
  if (lane == 0) wsum[wave] = lsum;
  __syncthreads();
  if (tid == 0) atomicAdd(lossAcc, wsum[0] + wsum[1] + wsum[2] + wsum[3]);
  if (wave == 0) {
    float h = Hrow[base + lane];
    #pragma unroll
    for (int off = 1; off < 64; off <<= 1) h += __shfl_xor(h, off, 64);
    if (lane == 0) atomicAdd(hAcc, h);
  }
}

__global__ void finalize_kernel(const float* lossAcc, const float* hAcc,
                                float* out, size_t M, float invBD, float invB) {
  if (threadIdx.x == 0) {
    float L = *lossAcc * invBD;
    out[M] = L;
    out[M + 1] = L;
    out[M + 2] = *hAcc * invB;
  }
}

extern "C" void kernel_launch(void* const* d_in, const int* in_sizes, int n_in,
                              void* d_out, int out_size, void* d_ws, size_t ws_size,
                              hipStream_t stream) {
  (void)n_in; (void)out_size; (void)ws_size;
  const float* feat = (const float*)d_in[0];
  const float* cb   = (const float*)d_in[1];
  const int B = in_sizes[0] / DDIM;  // 32768
  const int C = in_sizes[1] / DDIM;  // 8192
  float* out = (float*)d_out;

  unsigned short* cbhi = (unsigned short*)d_ws;          // C*DDIM bf16
  unsigned short* cblo = cbhi + (size_t)C * DDIM;        // C*DDIM bf16
  float* cn      = (float*)(cblo + (size_t)C * DDIM);    // C
  float* Hrow    = cn + C;                               // B
  int*   amin    = (int*)(Hrow + B);                     // B
  int*   flagged = amin + B;                             // B
  int*   flagCount = flagged + B;                        // 1
  float* lossAcc = (float*)(flagCount + 1);              // 1
  float* hAcc    = lossAcc + 1;                          // 1

  init_kernel<<<1, 64, 0, stream>>>(flagCount, lossAcc, hAcc);
  cvt_cb_kernel<<<(C * DDIM) / (256 * 8), 256, 0, stream>>>(cb, cbhi, cblo);
  cn_kernel<<<C / 4, 256, 0, stream>>>(cb, cn);
  dist_kernel<<<B / BM, 256, 0, stream>>>(feat, cbhi, cblo, cn, Hrow, amin,
                                          flagged, flagCount, C);
  refine_kernel<<<256, 256, 0, stream>>>(feat, cb, amin, flagged, flagCount, C);
  gather_kernel<<<B / 64, 256, 0, stream>>>(feat, cb, amin, Hrow, out, lossAcc, hAcc);
  finalize_kernel<<<1, 64, 0, stream>>>(lossAcc, hAcc, out,
                                        (size_t)B * DDIM,
                                        1.0f / ((float)B * (float)DDIM),
                                        1.0f / (float)B);
}